// Round 4
// baseline (215.881 us; speedup 1.0000x reference)
//
#include <hip/hip_runtime.h>
#include <hip/hip_fp16.h>
#include <math.h>

#define NODES   100000
#define EDGES   1200000
#define GRAPHS  512
#define DIM     64
#define NT      10
#define KTOT    576     // 64 base + 64*8 spline features

#define NB      512     // sort buckets: bucket = dst >> 8; 391 populated
#define NBUSED  391     // populated buckets = ceil(NODES/256)
#define EPB     4096    // edges per s3 block
// CAP: populated-bucket mean = 1.2M/391 = 3070 (sigma ~55) + per-node x4
// padding (<= 768) -> 4608 gives ~10 sigma headroom.
#define CAP     4608

// K-chunked weight staging: 9 stages x 64 k-values (2 MFMA steps each)
#define KSTAGE     64
#define WTL_STRIDE 72   // 64 shorts + 8 pad
#define V_STRIDE   72   // padded fp16 row stride for v in LDS

// mega-kernel block ranges (512 threads each)
#define S3B     ((EDGES + EPB - 1) / EPB)              // 293
#define PREPB   ((2 * DIM * KTOT) / 512)               // 144
#define CONVB   ((NODES * 16 + 32 + 511) / 512)        // 3126

typedef _Float16 f16x8  __attribute__((ext_vector_type(8)));   // MFMA A/B frag
typedef __fp16   fp16x2 __attribute__((ext_vector_type(2)));   // cvt_pkrtz result
typedef __attribute__((ext_vector_type(4))) float frag_cd;     // 4 fp32 acc

__device__ __forceinline__ float silu(float x) {
    // x * rcp(1+e^-x): v_rcp_f32 instead of IEEE div sequence
    return x * __builtin_amdgcn_rcpf(1.f + __expf(-x));
}

__device__ __forceinline__ unsigned packh2(float a, float b) {
    fp16x2 h = __builtin_amdgcn_cvt_pkrtz(a, b);
    return __builtin_bit_cast(unsigned, h);
}

// 8 packed fp16 viewed as 4 half2 for v_pk_add_f16 accumulation
union H8 { uint4 u; __half2 h[4]; };

// ---------------------------------------------------------------------------
// Cubic B-spline bases for one dim as packed fp16x8 A-fragment.
// Horner-factored cardinal weights (shared u^2/u^3 powers).
// ---------------------------------------------------------------------------
__device__ __forceinline__ f16x8 bases_frag(float xv) {
    float tt  = fmaf(xv, 2.5f, 5.5f);
    float fm  = floorf(tt);
    int   m   = (int)fm;
    float u   = tt - fm;
    float u2  = u * u;
    float u3  = u2 * u;
    float v0  = fmaf(fmaf(fmaf(u, -(1.f / 6.f), 0.5f), u, -0.5f), u, 1.f / 6.f); // (1-u)^3/6
    float v1  = fmaf(u3, 0.5f, fmaf(u2, -1.f, 2.f / 3.f));                       // (3u^3-6u^2+4)/6
    float v2  = fmaf(u + u2 - u3, 0.5f, 1.f / 6.f);                              // (-3u^3+3u^2+3u+1)/6
    float v3  = u3 * (1.f / 6.f);

    unsigned d0 = packh2(v0, v1);
    unsigned d1 = packh2(v2, v3);
    int p = m - 3;
    int B = p >> 1;
    bool odd = (p & 1) != 0;
    unsigned e1 = __builtin_amdgcn_alignbit(d1, d0, 16);   // [v1,v2]
    unsigned W0 = odd ? (d0 << 16) : d0;
    unsigned W1 = odd ? e1 : d1;
    unsigned W2 = odd ? (d1 >> 16) : 0u;
    union { f16x8 f; unsigned u[4]; } r;
    r.u[0] = (B == 0) ? W0 : ((B == -1) ? W1 : ((B == -2) ? W2 : 0u));
    r.u[1] = (B == 1) ? W0 : ((B ==  0) ? W1 : ((B == -1) ? W2 : 0u));
    r.u[2] = (B == 2) ? W0 : ((B ==  1) ? W1 : ((B ==  0) ? W2 : 0u));
    r.u[3] = (B == 3) ? W0 : ((B ==  2) ? W1 : ((B ==  1) ? W2 : 0u));
    return r.f;
}

// ===========================================================================
// Mega kernel: three independent phases by block range (512 threads each).
//   [0, S3B)               : s3 edge partition with LDS local sort
//   [S3B, S3B+PREPB)       : fp16 W_T prep for both layers
//   [S3B+PREPB, +CONVB)    : x fp32->fp16 conv + pad rows
// ===========================================================================
__global__ __launch_bounds__(512) void mega(const int* __restrict__ ei,
                                            int* __restrict__ bcur,
                                            unsigned* __restrict__ tmp,
                                            const float* __restrict__ bw0,
                                            const float* __restrict__ sw0,
                                            const float* __restrict__ sc0,
                                            const float* __restrict__ bw1,
                                            const float* __restrict__ sw1,
                                            const float* __restrict__ sc1,
                                            unsigned short* __restrict__ wt0,
                                            unsigned short* __restrict__ wt1,
                                            const float* __restrict__ x,
                                            unsigned short* __restrict__ xb,
                                            unsigned short* __restrict__ hpad) {
    __shared__ int hist[NB], lstart[NB], gbase[NB], cur[NB];   // 8 KB
    __shared__ unsigned ebuf[EPB];                             // 16 KB
    __shared__ unsigned short bk[EPB];                         //  8 KB
    const int bx = blockIdx.x;
    const int t  = threadIdx.x;

    if (bx < S3B) {
        // ---- s3: partition EPB edges into bucket slabs, LDS-local sort ----
        hist[t] = 0; cur[t] = 0;
        __syncthreads();
        const int e0 = bx * EPB;
        int src[8], dst[8];
#pragma unroll
        for (int k = 0; k < 8; ++k) {
            int e = e0 + t + k * 512;
            bool valid = e < EDGES;
            src[k] = valid ? ei[e] : 0;
            dst[k] = valid ? ei[EDGES + e] : -1;
            if (valid) atomicAdd(&hist[dst[k] >> 8], 1);
        }
        __syncthreads();
        // exclusive scan of hist -> lstart (chunk start within ebuf)
        int v = hist[t];
        lstart[t] = v;
        __syncthreads();
        int run = v;
        for (int d = 1; d < NB; d <<= 1) {
            int a = (t >= d) ? lstart[t - d] : 0;
            __syncthreads();
            run += a; lstart[t] = run;
            __syncthreads();
        }
        lstart[t] = run - v;          // own-element only; barrier below
        // global reservation
        if (v) gbase[t] = atomicAdd(&bcur[t], v);
        __syncthreads();
        // scatter regs -> LDS (bucket-contiguous)
#pragma unroll
        for (int k = 0; k < 8; ++k) {
            if (dst[k] >= 0) {
                int b = dst[k] >> 8;
                int pos = lstart[b] + atomicAdd(&cur[b], 1);
                ebuf[pos] = (unsigned)src[k] | ((unsigned)(dst[k] & 255) << 24);
                bk[pos] = (unsigned short)b;
            }
        }
        __syncthreads();
        // linear sweep: consecutive i -> consecutive slab addresses
        int total = EDGES - e0; if (total > EPB) total = EPB;
        for (int i = t; i < total; i += 512) {
            int b = bk[i];
            tmp[(size_t)b * CAP + gbase[b] + (i - lstart[b])] = ebuf[i];
        }
        return;
    }

    if (bx < S3B + PREPB) {
        // ---- weight prep ----
        int idx = (bx - S3B) * 512 + t;
        int layer = idx >= DIM * KTOT;
        int li = layer ? idx - DIM * KTOT : idx;
        const float* bw = layer ? bw1 : bw0;
        const float* sw = layer ? sw1 : sw0;
        const float* sc = layer ? sc1 : sc0;
        unsigned short* wt = layer ? wt1 : wt0;
        int o = li / KTOT, k = li % KTOT;
        float v;
        if (k < DIM) {
            v = bw[o * DIM + k];
        } else {
            int i = (k - DIM) >> 3, g = (k - DIM) & 7;
            v = sw[(o * DIM + i) * 8 + g] * sc[o * DIM + i];
        }
        wt[li] = __half_as_ushort(__float2half(v));
        return;
    }

    // ---- conv: x fp32 -> fp16, pad rows ----
    int i = (bx - S3B - PREPB) * 512 + t;
    if (i < NODES * 16) {
        float4 v = ((const float4*)x)[i];
        unsigned lo = packh2(v.x, v.y);
        unsigned hi = packh2(v.z, v.w);
        ((uint2*)xb)[i] = make_uint2(lo, hi);
    } else {
        int j = i - NODES * 16;
        if (j < 16)      ((uint2*)xb)[NODES * 16 + j] = make_uint2(0, 0);
        else if (j < 32) ((uint2*)hpad)[j - 16]       = make_uint2(0, 0);
    }
}

// ===========================================================================
// s4: per-bucket node-level counting sort -> rowp + padded col (sentinel
// NODES, segments x4) + 4 tail sentinels per bucket.
// ===========================================================================
__global__ __launch_bounds__(1024) void s4_fill(const unsigned* __restrict__ tmp,
                                                const int* __restrict__ bcur,
                                                int2* __restrict__ rowp,
                                                int* __restrict__ col) {
    __shared__ int deg[256], scanI[256], cur[256];
    __shared__ int tot;
    __shared__ int4 colbuf4[CAP / 4];          // 18.4 KB
    int* colbuf = (int*)colbuf4;
    const int b = blockIdx.x, t = threadIdx.x;
    const int cnt = bcur[b];
    const int base = b * CAP;
    if (t < 256) deg[t] = 0;
    __syncthreads();
    for (int i = t; i < cnt; i += 1024)
        atomicAdd(&deg[tmp[base + i] >> 24], 1);
    __syncthreads();
    if (t < 256) scanI[t] = (deg[t] + 3) & ~3;
    __syncthreads();
    for (int d = 1; d < 256; d <<= 1) {
        int a = 0;
        if (t < 256 && t >= d) a = scanI[t - d];
        __syncthreads();
        if (t < 256) scanI[t] += a;
        __syncthreads();
    }
    if (t < 256) {
        int pad = (deg[t] + 3) & ~3;
        int start = scanI[t] - pad;
        int ng = b * 256 + t;
        if (ng < NODES) rowp[ng] = make_int2(base + start, base + start + pad);
        cur[t] = start;
        if (t == 255) tot = scanI[255];
    }
    __syncthreads();
    for (int i = t; i < cnt; i += 1024) {
        unsigned p = tmp[base + i];
        int pos = atomicAdd(&cur[p >> 24], 1);
        colbuf[pos] = (int)(p & 0xFFFFFFu);
    }
    __syncthreads();
    if (t < 256) {
        int pad = (deg[t] + 3) & ~3;
        int end = scanI[t] - pad + pad;        // = scanI[t]
        for (int k = cur[t]; k < end; ++k) colbuf[k] = NODES;
    }
    __syncthreads();
    int nq = tot >> 2;
    int4* out4 = (int4*)(col + base);
    for (int i = t; i < nq; i += 1024) out4[i] = colbuf4[i];
    // tail sentinels (cheap insurance for any read-ahead)
    if (t < 4) col[base + tot + t] = NODES;
}

// ===========================================================================
// Fused GIN layer (fp16 storage, fp16 pk-add gather accum): guard-free gather
// with int4 col loads, 4 INDEPENDENT wide accumulators.
// NOTE: plain __launch_bounds__(256) -- NO min-waves arg.  Rounds 1-3 showed
// that (256,8) makes the allocator collapse to 32 VGPR, which serializes the
// four gather row-loads (VALUBusy 44%->21%, dur +50%).  Register headroom IS
// the gather's memory-level parallelism; do not cap it.
// MFMA KAN all 64 outputs, W_T in 9 K-chunks with register prefetch.
// POOL=1: skip h-store, accumulate fp32 into pooled[GRAPHS][DIM].
// ===========================================================================
template<int POOL>
__global__ __launch_bounds__(256) void fused_layer(const unsigned short* __restrict__ xin,
                                                   const int2* __restrict__ rowp,
                                                   const int* __restrict__ col,
                                                   const unsigned short* __restrict__ wt,
                                                   unsigned short* __restrict__ out,
                                                   const int* __restrict__ bat,
                                                   float* __restrict__ pooled) {
    __shared__ unsigned short wt_lds[64 * WTL_STRIDE];  // 9216 B
    __shared__ unsigned short v_lds[64 * V_STRIDE];     // 9216 B

    const int t     = threadIdx.x;
    const int nbase = blockIdx.x * 64;

    // ---- prefetch W chunk 0 into registers (2 uint4 per thread) ----
    uint4 p0, p1;
    {
        int c0 = t, c1 = t + 256;
        p0 = *(const uint4*)(wt + (c0 >> 3) * KTOT + (c0 & 7) * 8);
        p1 = *(const uint4*)(wt + (c1 >> 3) * KTOT + (c1 & 7) * 8);
    }

    // ---- fused gather: v[node] = x[node] + sum_{src} x[src] (fp16 pk-add) --
    const uint4* x4 = (const uint4*)xin;
#pragma unroll
    for (int rd = 0; rd < 2; ++rd) {
        int idx  = t + rd * 256;
        int node = idx >> 3, c8 = idx & 7;
        int n = nbase + node;
        uint4 res = make_uint4(0, 0, 0, 0);
        if (n < NODES) {
            int2 be = rowp[n];
            H8 a0, a1, a2, a3;
            a0.u = x4[n * 8 + c8];                         // self term as init
            a1.u = make_uint4(0, 0, 0, 0);
            a2.u = make_uint4(0, 0, 0, 0);
            a3.u = make_uint4(0, 0, 0, 0);
            for (int p = be.x; p < be.y; p += 4) {
                int4 c4 = *(const int4*)(col + p);
                H8 r0, r1, r2, r3;
                r0.u = x4[c4.x * 8 + c8];
                r1.u = x4[c4.y * 8 + c8];
                r2.u = x4[c4.z * 8 + c8];
                r3.u = x4[c4.w * 8 + c8];
#pragma unroll
                for (int j = 0; j < 4; ++j) {
                    a0.h[j] = __hadd2(a0.h[j], r0.h[j]);
                    a1.h[j] = __hadd2(a1.h[j], r1.h[j]);
                    a2.h[j] = __hadd2(a2.h[j], r2.h[j]);
                    a3.h[j] = __hadd2(a3.h[j], r3.h[j]);
                }
            }
#pragma unroll
            for (int j = 0; j < 4; ++j)
                a0.h[j] = __hadd2(__hadd2(a0.h[j], a1.h[j]), __hadd2(a2.h[j], a3.h[j]));
            res = a0.u;
        }
        *(uint4*)(v_lds + node * V_STRIDE + c8 * 8) = res;
    }
    // write chunk 0 to LDS
    {
        int c0 = t, c1 = t + 256;
        *(uint4*)(wt_lds + (c0 >> 3) * WTL_STRIDE + (c0 & 7) * 8) = p0;
        *(uint4*)(wt_lds + (c1 >> 3) * WTL_STRIDE + (c1 & 7) * 8) = p1;
    }
    __syncthreads();

    // ---- MFMA phase ----
    const int w = t >> 6;            // wave 0..3 -> nodes 16w..16w+15
    const int l = t & 63;
    const int q = l >> 4;            // k-quad
    const int c = l & 15;            // A row (node) / B row (output)
    const unsigned short* vrow = v_lds + ((w << 4) + c) * V_STRIDE;

    frag_cd ac0 = {0.f, 0.f, 0.f, 0.f};
    frag_cd ac1 = {0.f, 0.f, 0.f, 0.f};
    frag_cd ac2 = {0.f, 0.f, 0.f, 0.f};
    frag_cd ac3 = {0.f, 0.f, 0.f, 0.f};

#define MSTEP(OFF, A) {                                                          \
        f16x8 b0 = *(const f16x8*)(wt_lds + (c     ) * WTL_STRIDE + (OFF));      \
        f16x8 b1 = *(const f16x8*)(wt_lds + (c + 16) * WTL_STRIDE + (OFF));      \
        f16x8 b2 = *(const f16x8*)(wt_lds + (c + 32) * WTL_STRIDE + (OFF));      \
        f16x8 b3 = *(const f16x8*)(wt_lds + (c + 48) * WTL_STRIDE + (OFF));      \
        ac0 = __builtin_amdgcn_mfma_f32_16x16x32_f16(A, b0, ac0, 0, 0, 0);       \
        ac1 = __builtin_amdgcn_mfma_f32_16x16x32_f16(A, b1, ac1, 0, 0, 0);       \
        ac2 = __builtin_amdgcn_mfma_f32_16x16x32_f16(A, b2, ac2, 0, 0, 0);       \
        ac3 = __builtin_amdgcn_mfma_f32_16x16x32_f16(A, b3, ac3, 0, 0, 0); }

    // prefetch chunk 1 (in flight during chunk-0 compute)
    {
        int c0 = t, c1 = t + 256;
        p0 = *(const uint4*)(wt + (c0 >> 3) * KTOT + KSTAGE + (c0 & 7) * 8);
        p1 = *(const uint4*)(wt + (c1 >> 3) * KTOT + KSTAGE + (c1 & 7) * 8);
    }

    // chunk 0: silu base features k = 0..63 (2 MFMA steps)
#pragma unroll
    for (int s = 0; s < 2; ++s) {
        f16x8 hv = *(const f16x8*)(vrow + 32 * s + 8 * q);
        float f[8];
#pragma unroll
        for (int j = 0; j < 8; ++j) f[j] = silu((float)hv[j]);
        union { f16x8 v; unsigned u[4]; } a;
#pragma unroll
        for (int j = 0; j < 4; ++j) a.u[j] = packh2(f[2 * j], f[2 * j + 1]);
        MSTEP(32 * s + 8 * q, a.v);
    }

    // chunks 1..8: barrier, commit prefetched chunk, prefetch next, 2 steps
#pragma unroll
    for (int st = 1; st < 9; ++st) {
        __syncthreads();
        {
            int c0 = t, c1 = t + 256;
            *(uint4*)(wt_lds + (c0 >> 3) * WTL_STRIDE + (c0 & 7) * 8) = p0;
            *(uint4*)(wt_lds + (c1 >> 3) * WTL_STRIDE + (c1 & 7) * 8) = p1;
        }
        __syncthreads();
        if (st < 8) {
            int c0 = t, c1 = t + 256;
            p0 = *(const uint4*)(wt + (c0 >> 3) * KTOT + (st + 1) * KSTAGE + (c0 & 7) * 8);
            p1 = *(const uint4*)(wt + (c1 >> 3) * KTOT + (st + 1) * KSTAGE + (c1 & 7) * 8);
        }
#pragma unroll
        for (int k2 = 0; k2 < 2; ++k2) {
            // dim handled by this step: d = 8*(st-1) + 4*k2 + q
            f16x8 a = bases_frag((float)(*(const _Float16*)(vrow + 8 * (st - 1) + 4 * k2 + q)));
            MSTEP(32 * k2 + 8 * q, a);
        }
    }
#undef MSTEP

    // ---- epilogue: C/D rows = nodes n0..n0+3, cols = c + 16*acc ----
    const int n0 = nbase + (w << 4) + (q << 2);
    if (POOL == 0) {
#pragma unroll
        for (int r = 0; r < 4; ++r) {
            int n = n0 + r;
            if (n < NODES) {
                unsigned short* o = out + (size_t)n * DIM + c;
                o[0]  = __half_as_ushort(__float2half(ac0[r]));
                o[16] = __half_as_ushort(__float2half(ac1[r]));
                o[32] = __half_as_ushort(__float2half(ac2[r]));
                o[48] = __half_as_ushort(__float2half(ac3[r]));
            }
        }
    } else {
        bool full = (n0 + 3 < NODES);
        int g0 = full ? bat[n0] : 0;
        int g3 = full ? bat[n0 + 3] : -1;
        if (full && g0 == g3) {
            // fast path: all 4 rows in same graph -> 4 atomics
            float* pp = pooled + g0 * DIM + c;
            atomicAdd(pp,      ac0[0] + ac0[1] + ac0[2] + ac0[3]);
            atomicAdd(pp + 16, ac1[0] + ac1[1] + ac1[2] + ac1[3]);
            atomicAdd(pp + 32, ac2[0] + ac2[1] + ac2[2] + ac2[3]);
            atomicAdd(pp + 48, ac3[0] + ac3[1] + ac3[2] + ac3[3]);
        } else {
#pragma unroll
            for (int r = 0; r < 4; ++r) {
                int n = n0 + r;
                if (n < NODES) {
                    int g = bat[n];
                    float* pp = pooled + g * DIM + c;
                    atomicAdd(pp,      ac0[r]);
                    atomicAdd(pp + 16, ac1[r]);
                    atomicAdd(pp + 32, ac2[r]);
                    atomicAdd(pp + 48, ac3[r]);
                }
            }
        }
    }
}

// ---------------------------------------------------------------------------
// Head: KAN on pooled[GRAPHS][DIM] (one wave per graph).
// ---------------------------------------------------------------------------
__global__ __launch_bounds__(64) void head_k(const float* __restrict__ pooled,
                                             const float* __restrict__ bwh,
                                             const float* __restrict__ swh,
                                             const float* __restrict__ sch,
                                             float* __restrict__ out) {
    const int g = blockIdx.x, i = threadIdx.x;
    float xv = pooled[g * DIM + i];

    float s  = silu(xv);
    float tt  = fmaf(xv, 2.5f, 5.5f);
    float fm  = floorf(tt);
    int   m   = (int)fm;
    float u   = tt - fm;
    float u2  = u * u;
    float u3  = u2 * u;
    float v0  = fmaf(fmaf(fmaf(u, -(1.f / 6.f), 0.5f), u, -0.5f), u, 1.f / 6.f);
    float v1  = fmaf(u3, 0.5f, fmaf(u2, -1.f, 2.f / 3.f));
    float v2  = fmaf(u + u2 - u3, 0.5f, 1.f / 6.f);
    float v3  = u3 * (1.f / 6.f);
    bool inr  = (m >= 0) && (m <= 10);
    float b[8];
#pragma unroll
    for (int j = 0; j < 8; ++j) {
        float bv = 0.f;
        bv = (j == m - 3) ? v0 : bv;
        bv = (j == m - 2) ? v1 : bv;
        bv = (j == m - 1) ? v2 : bv;
        bv = (j == m)     ? v3 : bv;
        b[j] = inr ? bv : 0.f;
    }

    float part[NT];
#pragma unroll
    for (int o = 0; o < NT; ++o) {
        const float* sp = swh + (o * DIM + i) * 8;
        float sb = 0.f;
#pragma unroll
        for (int qq = 0; qq < 8; ++qq) sb = fmaf(b[qq], sp[qq], sb);
        part[o] = fmaf(s, bwh[o * DIM + i], sb * sch[o * DIM + i]);
    }
#pragma unroll
    for (int o = 0; o < NT; ++o) {
        float v = part[o];
#pragma unroll
        for (int off = 32; off > 0; off >>= 1) v += __shfl_down(v, off, 64);
        if (i == 0) out[g * NT + o] = v;
    }
}

// ---------------------------------------------------------------------------
extern "C" void kernel_launch(void* const* d_in, const int* in_sizes, int n_in,
                              void* d_out, int out_size, void* d_ws, size_t ws_size,
                              hipStream_t stream) {
    const float* x   = (const float*)d_in[0];
    const int*   ei  = (const int*)d_in[1];
    const int*   bat = (const int*)d_in[2];
    const float* bw0 = (const float*)d_in[3];
    const float* sw0 = (const float*)d_in[4];
    const float* sc0 = (const float*)d_in[5];
    const float* bw1 = (const float*)d_in[6];
    const float* sw1 = (const float*)d_in[7];
    const float* sc1 = (const float*)d_in[8];
    const float* bwh = (const float*)d_in[9];
    const float* swh = (const float*)d_in[10];
    const float* sch = (const float*)d_in[11];
    float* out = (float*)d_out;

    const size_t ROW = (size_t)(NODES + 1) * DIM;   // +1 zero row for gather pad

    // ---- workspace layout (16B-aligned sections) ----
    unsigned short* wt0 = (unsigned short*)d_ws;                 // 36864 fp16
    unsigned short* wt1 = wt0 + DIM * KTOT;                      // 36864 fp16
    unsigned short* xbf = wt1 + DIM * KTOT;                      // ROW fp16
    unsigned short* hbf = xbf + ROW;                             // ROW fp16 (layer0 out)
    int2* rowp    = (int2*)(hbf + ROW);                          // NODES int2
    int* col      = (int*)(rowp + NODES);                        // NB*CAP i
    int* bcur     = col + (size_t)NB * CAP;                      // NB i
    float* pooled = (float*)(bcur + NB);                         // GRAPHS*DIM f32
    unsigned* tmp = (unsigned*)(pooled + (size_t)GRAPHS * DIM);  // NB*CAP u32

    // zero bcur + pooled in one contiguous memset
    (void)hipMemsetAsync(bcur, 0, NB * sizeof(int) + (size_t)GRAPHS * DIM * sizeof(float), stream);

    mega<<<S3B + PREPB + CONVB, 512, 0, stream>>>(
        ei, bcur, tmp,
        bw0, sw0, sc0, bw1, sw1, sc1, wt0, wt1,
        x, xbf, hbf + (size_t)NODES * DIM);

    s4_fill<<<NBUSED, 1024, 0, stream>>>(tmp, bcur, rowp, col);

    const int layer_blocks = (NODES + 63) / 64;        // 1563
    fused_layer<0><<<layer_blocks, 256, 0, stream>>>(xbf, rowp, col, wt0, hbf, nullptr, nullptr);
    fused_layer<1><<<layer_blocks, 256, 0, stream>>>(hbf, rowp, col, wt1, nullptr, bat, pooled);

    head_k<<<GRAPHS, 64, 0, stream>>>(pooled, bwh, swh, sch, out);
}

// Round 5
// 198.435 us; speedup vs baseline: 1.0879x; 1.0879x over previous
//
#include <hip/hip_runtime.h>
#include <hip/hip_fp16.h>
#include <math.h>

#define NODES   100000
#define EDGES   1200000
#define GRAPHS  512
#define DIM     64
#define NT      10
#define KTOT    576     // 64 base + 64*8 spline features

#define NB      512     // sort buckets: bucket = dst >> 8; 391 populated
#define NBUSED  391     // populated buckets = ceil(NODES/256)
#define EPB     4096    // edges per s3 block
// CAP: populated-bucket mean = 1.2M/391 = 3070 (sigma ~55) + per-node x4
// padding (<= 768) -> 4608 gives ~10 sigma headroom.
#define CAP     4608

// K-chunked weight staging: 9 stages x 64 k-values (2 MFMA steps each)
#define KSTAGE     64
#define WTL_STRIDE 72   // 64 shorts + 8 pad
#define V_STRIDE   72   // padded fp16 row stride for v in LDS

// mega-kernel block ranges (512 threads each)
#define S3B     ((EDGES + EPB - 1) / EPB)              // 293
#define PREPB   ((2 * DIM * KTOT) / 512)               // 144
#define CONVB   ((NODES * 16 + 32 + 511) / 512)        // 3126

typedef _Float16 f16x8  __attribute__((ext_vector_type(8)));   // MFMA A/B frag
typedef __fp16   fp16x2 __attribute__((ext_vector_type(2)));   // cvt_pkrtz result
typedef __attribute__((ext_vector_type(4))) float frag_cd;     // 4 fp32 acc

__device__ __forceinline__ float silu(float x) {
    // x * rcp(1+e^-x): v_rcp_f32 instead of IEEE div sequence
    return x * __builtin_amdgcn_rcpf(1.f + __expf(-x));
}

__device__ __forceinline__ unsigned packh2(float a, float b) {
    fp16x2 h = __builtin_amdgcn_cvt_pkrtz(a, b);
    return __builtin_bit_cast(unsigned, h);
}

// 8 packed fp16 viewed as 4 half2 for v_pk_add_f16 accumulation
union H8 { uint4 u; __half2 h[4]; };

// ---------------------------------------------------------------------------
// Cubic B-spline bases for one dim as packed fp16x8 A-fragment.
// Horner-factored cardinal weights (shared u^2/u^3 powers).
// ---------------------------------------------------------------------------
__device__ __forceinline__ f16x8 bases_frag(float xv) {
    float tt  = fmaf(xv, 2.5f, 5.5f);
    float fm  = floorf(tt);
    int   m   = (int)fm;
    float u   = tt - fm;
    float u2  = u * u;
    float u3  = u2 * u;
    float v0  = fmaf(fmaf(fmaf(u, -(1.f / 6.f), 0.5f), u, -0.5f), u, 1.f / 6.f); // (1-u)^3/6
    float v1  = fmaf(u3, 0.5f, fmaf(u2, -1.f, 2.f / 3.f));                       // (3u^3-6u^2+4)/6
    float v2  = fmaf(u + u2 - u3, 0.5f, 1.f / 6.f);                              // (-3u^3+3u^2+3u+1)/6
    float v3  = u3 * (1.f / 6.f);

    unsigned d0 = packh2(v0, v1);
    unsigned d1 = packh2(v2, v3);
    int p = m - 3;
    int B = p >> 1;
    bool odd = (p & 1) != 0;
    unsigned e1 = __builtin_amdgcn_alignbit(d1, d0, 16);   // [v1,v2]
    unsigned W0 = odd ? (d0 << 16) : d0;
    unsigned W1 = odd ? e1 : d1;
    unsigned W2 = odd ? (d1 >> 16) : 0u;
    union { f16x8 f; unsigned u[4]; } r;
    r.u[0] = (B == 0) ? W0 : ((B == -1) ? W1 : ((B == -2) ? W2 : 0u));
    r.u[1] = (B == 1) ? W0 : ((B ==  0) ? W1 : ((B == -1) ? W2 : 0u));
    r.u[2] = (B == 2) ? W0 : ((B ==  1) ? W1 : ((B ==  0) ? W2 : 0u));
    r.u[3] = (B == 3) ? W0 : ((B ==  2) ? W1 : ((B ==  1) ? W2 : 0u));
    return r.f;
}

// ===========================================================================
// Mega kernel: three independent phases by block range (512 threads each).
//   [0, S3B)               : s3 edge partition with LDS local sort
//   [S3B, S3B+PREPB)       : fp16 W_T prep for both layers
//   [S3B+PREPB, +CONVB)    : x fp32->fp16 conv + pad rows + graph offsets
// ===========================================================================
__global__ __launch_bounds__(512) void mega(const int* __restrict__ ei,
                                            int* __restrict__ bcur,
                                            unsigned* __restrict__ tmp,
                                            const float* __restrict__ bw0,
                                            const float* __restrict__ sw0,
                                            const float* __restrict__ sc0,
                                            const float* __restrict__ bw1,
                                            const float* __restrict__ sw1,
                                            const float* __restrict__ sc1,
                                            unsigned short* __restrict__ wt0,
                                            unsigned short* __restrict__ wt1,
                                            const float* __restrict__ x,
                                            const int* __restrict__ bat,
                                            unsigned short* __restrict__ xb,
                                            unsigned short* __restrict__ hpad,
                                            int* __restrict__ goff) {
    __shared__ int hist[NB], lstart[NB], gbase[NB], cur[NB];   // 8 KB
    __shared__ unsigned ebuf[EPB];                             // 16 KB
    __shared__ unsigned short bk[EPB];                         //  8 KB
    const int bx = blockIdx.x;
    const int t  = threadIdx.x;

    if (bx < S3B) {
        // ---- s3: partition EPB edges into bucket slabs, LDS-local sort ----
        hist[t] = 0; cur[t] = 0;
        __syncthreads();
        const int e0 = bx * EPB;
        int src[8], dst[8];
#pragma unroll
        for (int k = 0; k < 8; ++k) {
            int e = e0 + t + k * 512;
            bool valid = e < EDGES;
            src[k] = valid ? ei[e] : 0;
            dst[k] = valid ? ei[EDGES + e] : -1;
            if (valid) atomicAdd(&hist[dst[k] >> 8], 1);
        }
        __syncthreads();
        // exclusive scan of hist -> lstart (chunk start within ebuf)
        int v = hist[t];
        lstart[t] = v;
        __syncthreads();
        int run = v;
        for (int d = 1; d < NB; d <<= 1) {
            int a = (t >= d) ? lstart[t - d] : 0;
            __syncthreads();
            run += a; lstart[t] = run;
            __syncthreads();
        }
        lstart[t] = run - v;          // own-element only; barrier below
        // global reservation
        if (v) gbase[t] = atomicAdd(&bcur[t], v);
        __syncthreads();
        // scatter regs -> LDS (bucket-contiguous)
#pragma unroll
        for (int k = 0; k < 8; ++k) {
            if (dst[k] >= 0) {
                int b = dst[k] >> 8;
                int pos = lstart[b] + atomicAdd(&cur[b], 1);
                ebuf[pos] = (unsigned)src[k] | ((unsigned)(dst[k] & 255) << 24);
                bk[pos] = (unsigned short)b;
            }
        }
        __syncthreads();
        // linear sweep: consecutive i -> consecutive slab addresses
        int total = EDGES - e0; if (total > EPB) total = EPB;
        for (int i = t; i < total; i += 512) {
            int b = bk[i];
            tmp[(size_t)b * CAP + gbase[b] + (i - lstart[b])] = ebuf[i];
        }
        return;
    }

    if (bx < S3B + PREPB) {
        // ---- weight prep ----
        int idx = (bx - S3B) * 512 + t;
        int layer = idx >= DIM * KTOT;
        int li = layer ? idx - DIM * KTOT : idx;
        const float* bw = layer ? bw1 : bw0;
        const float* sw = layer ? sw1 : sw0;
        const float* sc = layer ? sc1 : sc0;
        unsigned short* wt = layer ? wt1 : wt0;
        int o = li / KTOT, k = li % KTOT;
        float v;
        if (k < DIM) {
            v = bw[o * DIM + k];
        } else {
            int i = (k - DIM) >> 3, g = (k - DIM) & 7;
            v = sw[(o * DIM + i) * 8 + g] * sc[o * DIM + i];
        }
        wt[li] = __half_as_ushort(__float2half(v));
        return;
    }

    // ---- conv: x fp32 -> fp16, pad rows, graph offsets ----
    int i = (bx - S3B - PREPB) * 512 + t;
    if (i < NODES * 16) {
        float4 v = ((const float4*)x)[i];
        unsigned lo = packh2(v.x, v.y);
        unsigned hi = packh2(v.z, v.w);
        ((uint2*)xb)[i] = make_uint2(lo, hi);
        if ((i & 15) == 0) {
            int n = i >> 4;
            int b  = bat[n];
            int bp = (n == 0) ? -1 : bat[n - 1];
            for (int g = bp + 1; g <= b; ++g) goff[g] = n;
        }
        if (i == 0) {
            int blast = bat[NODES - 1];
            for (int g = blast + 1; g <= GRAPHS; ++g) goff[g] = NODES;
        }
    } else {
        int j = i - NODES * 16;
        if (j < 16)      ((uint2*)xb)[NODES * 16 + j] = make_uint2(0, 0);
        else if (j < 32) ((uint2*)hpad)[j - 16]       = make_uint2(0, 0);
    }
}

// ===========================================================================
// s4: per-bucket node-level counting sort -> rowp + padded col (sentinel
// NODES, segments x4) + 4 tail sentinels per bucket.
// ===========================================================================
__global__ __launch_bounds__(1024) void s4_fill(const unsigned* __restrict__ tmp,
                                                const int* __restrict__ bcur,
                                                int2* __restrict__ rowp,
                                                int* __restrict__ col) {
    __shared__ int deg[256], scanI[256], cur[256];
    __shared__ int tot;
    __shared__ int4 colbuf4[CAP / 4];          // 18.4 KB
    int* colbuf = (int*)colbuf4;
    const int b = blockIdx.x, t = threadIdx.x;
    const int cnt = bcur[b];
    const int base = b * CAP;
    if (t < 256) deg[t] = 0;
    __syncthreads();
    for (int i = t; i < cnt; i += 1024)
        atomicAdd(&deg[tmp[base + i] >> 24], 1);
    __syncthreads();
    if (t < 256) scanI[t] = (deg[t] + 3) & ~3;
    __syncthreads();
    for (int d = 1; d < 256; d <<= 1) {
        int a = 0;
        if (t < 256 && t >= d) a = scanI[t - d];
        __syncthreads();
        if (t < 256) scanI[t] += a;
        __syncthreads();
    }
    if (t < 256) {
        int pad = (deg[t] + 3) & ~3;
        int start = scanI[t] - pad;
        int ng = b * 256 + t;
        if (ng < NODES) rowp[ng] = make_int2(base + start, base + start + pad);
        cur[t] = start;
        if (t == 255) tot = scanI[255];
    }
    __syncthreads();
    for (int i = t; i < cnt; i += 1024) {
        unsigned p = tmp[base + i];
        int pos = atomicAdd(&cur[p >> 24], 1);
        colbuf[pos] = (int)(p & 0xFFFFFFu);
    }
    __syncthreads();
    if (t < 256) {
        int pad = (deg[t] + 3) & ~3;
        int end = scanI[t] - pad + pad;        // = scanI[t]
        for (int k = cur[t]; k < end; ++k) colbuf[k] = NODES;
    }
    __syncthreads();
    int nq = tot >> 2;
    int4* out4 = (int4*)(col + base);
    for (int i = t; i < nq; i += 1024) out4[i] = colbuf4[i];
    // tail sentinels (cheap insurance for any read-ahead)
    if (t < 4) col[base + tot + t] = NODES;
}

// ===========================================================================
// Fused GIN layer -- EXACT round-1 form (measured ~39.5 us): fp16 storage,
// fp16 pk-add gather with 4 independent accumulators, store-out epilogue.
// Rounds 2-4 post-mortem: the ~61 us top-5 dispatches were the POOL=1
// (atomic-pooling) variant; this store variant ran ~39.5 us throughout.
// Global-atomic pooling (1.6M device-scope atomics on 32K addrs) cost ~22 us
// -- do NOT fuse pooling via atomics.
// ===========================================================================
__global__ __launch_bounds__(256, 8) void fused_layer(const unsigned short* __restrict__ xin,
                                                      const int2* __restrict__ rowp,
                                                      const int* __restrict__ col,
                                                      const unsigned short* __restrict__ wt,
                                                      unsigned short* __restrict__ out) {
    __shared__ unsigned short wt_lds[64 * WTL_STRIDE];  // 9216 B
    __shared__ unsigned short v_lds[64 * V_STRIDE];     // 9216 B

    const int t     = threadIdx.x;
    const int nbase = blockIdx.x * 64;

    // ---- prefetch W chunk 0 into registers (2 uint4 per thread) ----
    uint4 p0, p1;
    {
        int c0 = t, c1 = t + 256;
        p0 = *(const uint4*)(wt + (c0 >> 3) * KTOT + (c0 & 7) * 8);
        p1 = *(const uint4*)(wt + (c1 >> 3) * KTOT + (c1 & 7) * 8);
    }

    // ---- fused gather: v[node] = x[node] + sum_{src} x[src] (fp16 pk-add) --
    const uint4* x4 = (const uint4*)xin;
#pragma unroll
    for (int rd = 0; rd < 2; ++rd) {
        int idx  = t + rd * 256;
        int node = idx >> 3, c8 = idx & 7;
        int n = nbase + node;
        uint4 res = make_uint4(0, 0, 0, 0);
        if (n < NODES) {
            int2 be = rowp[n];
            H8 a0, a1, a2, a3;
            a0.u = x4[n * 8 + c8];                         // self term as init
            a1.u = make_uint4(0, 0, 0, 0);
            a2.u = make_uint4(0, 0, 0, 0);
            a3.u = make_uint4(0, 0, 0, 0);
            for (int p = be.x; p < be.y; p += 4) {
                int4 c4 = *(const int4*)(col + p);
                H8 r0, r1, r2, r3;
                r0.u = x4[c4.x * 8 + c8];
                r1.u = x4[c4.y * 8 + c8];
                r2.u = x4[c4.z * 8 + c8];
                r3.u = x4[c4.w * 8 + c8];
#pragma unroll
                for (int j = 0; j < 4; ++j) {
                    a0.h[j] = __hadd2(a0.h[j], r0.h[j]);
                    a1.h[j] = __hadd2(a1.h[j], r1.h[j]);
                    a2.h[j] = __hadd2(a2.h[j], r2.h[j]);
                    a3.h[j] = __hadd2(a3.h[j], r3.h[j]);
                }
            }
#pragma unroll
            for (int j = 0; j < 4; ++j)
                a0.h[j] = __hadd2(__hadd2(a0.h[j], a1.h[j]), __hadd2(a2.h[j], a3.h[j]));
            res = a0.u;
        }
        *(uint4*)(v_lds + node * V_STRIDE + c8 * 8) = res;
    }
    // write chunk 0 to LDS
    {
        int c0 = t, c1 = t + 256;
        *(uint4*)(wt_lds + (c0 >> 3) * WTL_STRIDE + (c0 & 7) * 8) = p0;
        *(uint4*)(wt_lds + (c1 >> 3) * WTL_STRIDE + (c1 & 7) * 8) = p1;
    }
    __syncthreads();

    // ---- MFMA phase ----
    const int w = t >> 6;            // wave 0..3 -> nodes 16w..16w+15
    const int l = t & 63;
    const int q = l >> 4;            // k-quad
    const int c = l & 15;            // A row (node) / B row (output)
    const unsigned short* vrow = v_lds + ((w << 4) + c) * V_STRIDE;

    frag_cd ac0 = {0.f, 0.f, 0.f, 0.f};
    frag_cd ac1 = {0.f, 0.f, 0.f, 0.f};
    frag_cd ac2 = {0.f, 0.f, 0.f, 0.f};
    frag_cd ac3 = {0.f, 0.f, 0.f, 0.f};

#define MSTEP(OFF, A) {                                                          \
        f16x8 b0 = *(const f16x8*)(wt_lds + (c     ) * WTL_STRIDE + (OFF));      \
        f16x8 b1 = *(const f16x8*)(wt_lds + (c + 16) * WTL_STRIDE + (OFF));      \
        f16x8 b2 = *(const f16x8*)(wt_lds + (c + 32) * WTL_STRIDE + (OFF));      \
        f16x8 b3 = *(const f16x8*)(wt_lds + (c + 48) * WTL_STRIDE + (OFF));      \
        ac0 = __builtin_amdgcn_mfma_f32_16x16x32_f16(A, b0, ac0, 0, 0, 0);       \
        ac1 = __builtin_amdgcn_mfma_f32_16x16x32_f16(A, b1, ac1, 0, 0, 0);       \
        ac2 = __builtin_amdgcn_mfma_f32_16x16x32_f16(A, b2, ac2, 0, 0, 0);       \
        ac3 = __builtin_amdgcn_mfma_f32_16x16x32_f16(A, b3, ac3, 0, 0, 0); }

    // prefetch chunk 1 (in flight during chunk-0 compute)
    {
        int c0 = t, c1 = t + 256;
        p0 = *(const uint4*)(wt + (c0 >> 3) * KTOT + KSTAGE + (c0 & 7) * 8);
        p1 = *(const uint4*)(wt + (c1 >> 3) * KTOT + KSTAGE + (c1 & 7) * 8);
    }

    // chunk 0: silu base features k = 0..63 (2 MFMA steps)
#pragma unroll
    for (int s = 0; s < 2; ++s) {
        f16x8 hv = *(const f16x8*)(vrow + 32 * s + 8 * q);
        float f[8];
#pragma unroll
        for (int j = 0; j < 8; ++j) f[j] = silu((float)hv[j]);
        union { f16x8 v; unsigned u[4]; } a;
#pragma unroll
        for (int j = 0; j < 4; ++j) a.u[j] = packh2(f[2 * j], f[2 * j + 1]);
        MSTEP(32 * s + 8 * q, a.v);
    }

    // chunks 1..8: barrier, commit prefetched chunk, prefetch next, 2 steps
#pragma unroll
    for (int st = 1; st < 9; ++st) {
        __syncthreads();
        {
            int c0 = t, c1 = t + 256;
            *(uint4*)(wt_lds + (c0 >> 3) * WTL_STRIDE + (c0 & 7) * 8) = p0;
            *(uint4*)(wt_lds + (c1 >> 3) * WTL_STRIDE + (c1 & 7) * 8) = p1;
        }
        __syncthreads();
        if (st < 8) {
            int c0 = t, c1 = t + 256;
            p0 = *(const uint4*)(wt + (c0 >> 3) * KTOT + (st + 1) * KSTAGE + (c0 & 7) * 8);
            p1 = *(const uint4*)(wt + (c1 >> 3) * KTOT + (st + 1) * KSTAGE + (c1 & 7) * 8);
        }
#pragma unroll
        for (int k2 = 0; k2 < 2; ++k2) {
            // dim handled by this step: d = 8*(st-1) + 4*k2 + q
            f16x8 a = bases_frag((float)(*(const _Float16*)(vrow + 8 * (st - 1) + 4 * k2 + q)));
            MSTEP(32 * k2 + 8 * q, a);
        }
    }
#undef MSTEP

    // ---- store fp16: C/D rows = nodes, cols = c + 16*acc ----
    const int n0 = nbase + (w << 4) + (q << 2);
#pragma unroll
    for (int r = 0; r < 4; ++r) {
        int n = n0 + r;
        if (n < NODES) {
            unsigned short* o = out + (size_t)n * DIM + c;
            o[0]  = __half_as_ushort(__float2half(ac0[r]));
            o[16] = __half_as_ushort(__float2half(ac1[r]));
            o[32] = __half_as_ushort(__float2half(ac2[r]));
            o[48] = __half_as_ushort(__float2half(ac3[r]));
        }
    }
}

// ---------------------------------------------------------------------------
// Fused pool + head: one block per graph.  v2: uint4 (16B/lane) h-loads --
// round-0/1 version used 4B __half2 loads and cost ~10 us; this is the fix.
// 32 groups x 8 c8-slices; LDS 32x64 reduction; head math on t<64.
// ---------------------------------------------------------------------------
__global__ __launch_bounds__(256) void pool_head(const unsigned short* __restrict__ h,
                                                 const int* __restrict__ goff,
                                                 const float* __restrict__ bwh,
                                                 const float* __restrict__ swh,
                                                 const float* __restrict__ sch,
                                                 float* __restrict__ out) {
    __shared__ float red[32][64];
    const int g = blockIdx.x, t = threadIdx.x;
    const int start = goff[g], end = goff[g + 1];
    const int grp = t >> 3, c8 = t & 7;
    const uint4* h4 = (const uint4*)h;

    float f[8];
#pragma unroll
    for (int j = 0; j < 8; ++j) f[j] = 0.f;
    for (int n = start + grp; n < end; n += 32) {
        H8 v; v.u = h4[n * 8 + c8];
#pragma unroll
        for (int j = 0; j < 4; ++j) {
            float2 fj = __half22float2(v.h[j]);
            f[2 * j]     += fj.x;
            f[2 * j + 1] += fj.y;
        }
    }
#pragma unroll
    for (int j = 0; j < 8; ++j) red[grp][c8 * 8 + j] = f[j];
    __syncthreads();

    if (t < 64) {
        const int i = t;
        float xv = 0.f;
#pragma unroll
        for (int k = 0; k < 32; ++k) xv += red[k][i];

        float s  = silu(xv);
        float tt  = fmaf(xv, 2.5f, 5.5f);
        float fm  = floorf(tt);
        int   m   = (int)fm;
        float u   = tt - fm;
        float u2  = u * u;
        float u3  = u2 * u;
        float v0  = fmaf(fmaf(fmaf(u, -(1.f / 6.f), 0.5f), u, -0.5f), u, 1.f / 6.f);
        float v1  = fmaf(u3, 0.5f, fmaf(u2, -1.f, 2.f / 3.f));
        float v2  = fmaf(u + u2 - u3, 0.5f, 1.f / 6.f);
        float v3  = u3 * (1.f / 6.f);
        bool inr  = (m >= 0) && (m <= 10);
        float b[8];
#pragma unroll
        for (int j = 0; j < 8; ++j) {
            float bv = 0.f;
            bv = (j == m - 3) ? v0 : bv;
            bv = (j == m - 2) ? v1 : bv;
            bv = (j == m - 1) ? v2 : bv;
            bv = (j == m)     ? v3 : bv;
            b[j] = inr ? bv : 0.f;
        }

        float part[NT];
#pragma unroll
        for (int o = 0; o < NT; ++o) {
            const float* sp = swh + (o * DIM + i) * 8;
            float sb = 0.f;
#pragma unroll
            for (int qq = 0; qq < 8; ++qq) sb = fmaf(b[qq], sp[qq], sb);
            part[o] = fmaf(s, bwh[o * DIM + i], sb * sch[o * DIM + i]);
        }
#pragma unroll
        for (int o = 0; o < NT; ++o) {
            float v = part[o];
#pragma unroll
            for (int off = 32; off > 0; off >>= 1) v += __shfl_down(v, off, 64);
            if (i == 0) out[g * NT + o] = v;
        }
    }
}

// ---------------------------------------------------------------------------
extern "C" void kernel_launch(void* const* d_in, const int* in_sizes, int n_in,
                              void* d_out, int out_size, void* d_ws, size_t ws_size,
                              hipStream_t stream) {
    const float* x   = (const float*)d_in[0];
    const int*   ei  = (const int*)d_in[1];
    const int*   bat = (const int*)d_in[2];
    const float* bw0 = (const float*)d_in[3];
    const float* sw0 = (const float*)d_in[4];
    const float* sc0 = (const float*)d_in[5];
    const float* bw1 = (const float*)d_in[6];
    const float* sw1 = (const float*)d_in[7];
    const float* sc1 = (const float*)d_in[8];
    const float* bwh = (const float*)d_in[9];
    const float* swh = (const float*)d_in[10];
    const float* sch = (const float*)d_in[11];
    float* out = (float*)d_out;

    const size_t ROW = (size_t)(NODES + 1) * DIM;   // +1 zero row for gather pad

    // ---- workspace layout (16B-aligned sections) ----
    unsigned short* wt0 = (unsigned short*)d_ws;                 // 36864 fp16
    unsigned short* wt1 = wt0 + DIM * KTOT;                      // 36864 fp16
    unsigned short* xbf = wt1 + DIM * KTOT;                      // ROW fp16
    unsigned short* hbf = xbf + ROW;                             // ROW fp16 (layer0 out)
    unsigned short* h2  = hbf + ROW;                             // NODES*DIM fp16
    int* goff     = (int*)(h2 + (size_t)NODES * DIM);            // 514 i (padded)
    int2* rowp    = (int2*)(goff + 514);                         // NODES int2
    int* col      = (int*)(rowp + NODES);                        // NB*CAP i
    int* bcur     = col + (size_t)NB * CAP;                      // NB i
    unsigned* tmp = (unsigned*)(bcur + NB);                      // NB*CAP u32

    (void)hipMemsetAsync(bcur, 0, NB * sizeof(int), stream);

    mega<<<S3B + PREPB + CONVB, 512, 0, stream>>>(
        ei, bcur, tmp,
        bw0, sw0, sc0, bw1, sw1, sc1, wt0, wt1,
        x, bat, xbf, hbf + (size_t)NODES * DIM, goff);

    s4_fill<<<NBUSED, 1024, 0, stream>>>(tmp, bcur, rowp, col);

    const int layer_blocks = (NODES + 63) / 64;        // 1563
    fused_layer<<<layer_blocks, 256, 0, stream>>>(xbf, rowp, col, wt0, hbf);
    fused_layer<<<layer_blocks, 256, 0, stream>>>(hbf, rowp, col, wt1, h2);

    pool_head<<<GRAPHS, 256, 0, stream>>>(h2, goff, bwh, swh, sch, out);
}